// Round 1
// baseline (747.465 us; speedup 1.0000x reference)
//
#include <hip/hip_runtime.h>
#include <hip/hip_bf16.h>
#include <stdint.h>

// Problem constants (fixed by the reference)
#define N_ 16384
#define M_ 4096
#define D_ 256
#define O_ 256

// Workspace layout (bytes)
#define WS_T    0            // float[N]      exp(sf+ba)
#define WS_U    (64*1024)    // float[M]      exp(sc)
#define WS_R    (80*1024)    // float[D]      colsum(Hc)
#define WS_HCT  (128*1024)   // ushort[D*M]   Hc^T in bf16 (2 MB)
#define WS_ATTN (4*1024*1024)// ushort[N*D]   attn_out in bf16 (8 MB)

typedef float  f32x4  __attribute__((ext_vector_type(4)));
typedef short  short8 __attribute__((ext_vector_type(8)));

// fp32 -> bf16 (RNE). Inputs are finite (random normals) so no NaN handling.
__device__ __forceinline__ short f2bf(float f) {
  uint32_t u = __float_as_uint(f);
  u += 0x7FFFu + ((u >> 16) & 1u);
  return (short)(u >> 16);
}

// ---------------------------------------------------------------------------
// Prep 1: per-row dot with weight vector, then exp(dot + bias).
// One wave per row; lane l handles 4 consecutive elements (D=256 = 64*4).
__global__ __launch_bounds__(256) void rowdot_exp_kernel(
    const float* __restrict__ X, const float* __restrict__ w,
    const float* __restrict__ bias, float* __restrict__ outv) {
  int wv = threadIdx.x >> 6, lane = threadIdx.x & 63;
  int row = blockIdx.x * 4 + wv;
  const float4* x4 = (const float4*)(X + (size_t)row * D_);
  const float4* w4 = (const float4*)w;
  float4 xa = x4[lane], wa4 = w4[lane];
  float s = xa.x * wa4.x + xa.y * wa4.y + xa.z * wa4.z + xa.w * wa4.w;
#pragma unroll
  for (int off = 32; off > 0; off >>= 1) s += __shfl_xor(s, off);
  if (lane == 0) outv[row] = expf(s + (bias ? bias[0] : 0.0f));
}

// ---------------------------------------------------------------------------
// Prep 2: transpose Hc [M,D] fp32 -> HcT [D,M] bf16, and accumulate R = colsum(Hc).
// 64x64 tiles via padded LDS; R via one atomicAdd per column per block.
__global__ __launch_bounds__(256) void transpose_hc_kernel(
    const float* __restrict__ Hc, unsigned short* __restrict__ HcT,
    float* __restrict__ R) {
  __shared__ float tile[64][65];
  __shared__ float red[4][64];
  int bj = blockIdx.x & 63;        // 64 tiles along M
  int bd = blockIdx.x >> 6;        // 4 tiles along D
  int j0 = bj * 64, d0 = bd * 64;
  int t = threadIdx.x;
  float colsum = 0.0f;
#pragma unroll
  for (int i = 0; i < 16; ++i) {
    int e = t + 256 * i;
    int jj = e >> 6, dd = e & 63;             // dd == t&63 (constant per thread)
    float v = Hc[(size_t)(j0 + jj) * D_ + d0 + dd];
    tile[jj][dd] = v;
    colsum += v;
  }
  __syncthreads();
  red[t >> 6][t & 63] = colsum;
  __syncthreads();
  if (t < 64)
    atomicAdd(&R[d0 + t], red[0][t] + red[1][t] + red[2][t] + red[3][t]);
#pragma unroll
  for (int i = 0; i < 16; ++i) {
    int e = t + 256 * i;
    int dd = e >> 6, jj = e & 63;             // contiguous jj across lanes
    HcT[(size_t)(d0 + dd) * M_ + j0 + jj] = (unsigned short)f2bf(tile[jj][dd]);
  }
}

// ---------------------------------------------------------------------------
// Main fused kernel: C = A' @ Hc with A'_ij = adj_ij*(t_i*u_j - 1) built on the
// fly in registers (fragment-direct: each lane computes exactly its MFMA
// A-fragment elements). Row-sum of A' gives the softmax denominator for free.
// Epilogue: attn = (C + R)/(rowsum + M) + Hf, stored bf16.
// Block: 256 thr = 4 waves; wave (rtile=w&1 -> 16 rows, chalf=w>>1 -> 128 cols).
// BM=32, full 256-col width, grid = N/32 = 512 blocks (2/CU). No barriers in
// the K loop; depth-1 register prefetch keeps HBM reads in flight.
__global__ __launch_bounds__(256, 2) void main_gemm_kernel(
    const float* __restrict__ adj, const unsigned short* __restrict__ HcT,
    const float* __restrict__ tv, const float* __restrict__ uv,
    const float* __restrict__ Rv, const float* __restrict__ Hf,
    unsigned short* __restrict__ attnw) {
  __shared__ float u_lds[M_];
  __shared__ float Lrow[32];
  int tid = threadIdx.x;
  int w = tid >> 6, lane = tid & 63;
  int rtile = w & 1, chalf = w >> 1;
  int q = lane >> 4, m = lane & 15;
  int koff = q * 8;

  for (int i = tid; i < M_; i += 256) u_lds[i] = uv[i];

  int i0 = blockIdx.x * 32 + rtile * 16;
  float tl = tv[i0 + m];
  const float* adjrow = adj + (size_t)(i0 + m) * M_;
  int c0 = chalf * 128;

  f32x4 acc[8];
#pragma unroll
  for (int n = 0; n < 8; ++n) acc[n] = (f32x4){0.f, 0.f, 0.f, 0.f};
  float rs = 0.0f;

  const unsigned short* bbase[8];
#pragma unroll
  for (int n = 0; n < 8; ++n)
    bbase[n] = HcT + (size_t)(c0 + n * 16 + m) * M_ + koff;

  __syncthreads();  // u_lds ready (only barrier before epilogue)

  // prefetch k0 = 0
  float4 a0 = *(const float4*)(adjrow + koff);
  float4 a1 = *(const float4*)(adjrow + koff + 4);
  short8 bf[8];
#pragma unroll
  for (int n = 0; n < 8; ++n) bf[n] = *(const short8*)(bbase[n]);

  for (int k0 = 0; k0 < M_; k0 += 32) {
    int k1 = k0 + 32;
    int k1c = (k1 < M_) ? k1 : 0;  // last iter: harmless re-load of k=0
    float4 na0 = *(const float4*)(adjrow + k1c + koff);
    float4 na1 = *(const float4*)(adjrow + k1c + koff + 4);
    short8 nbf[8];
#pragma unroll
    for (int n = 0; n < 8; ++n) nbf[n] = *(const short8*)(bbase[n] + k1c);

    // transform current adj chunk -> A' fragment (8 bf16)
    float4 u0 = *(const float4*)&u_lds[k0 + koff];
    float4 u1 = *(const float4*)&u_lds[k0 + koff + 4];
    float ax[8] = {a0.x, a0.y, a0.z, a0.w, a1.x, a1.y, a1.z, a1.w};
    float ux[8] = {u0.x, u0.y, u0.z, u0.w, u1.x, u1.y, u1.z, u1.w};
    short8 af;
#pragma unroll
    for (int j = 0; j < 8; ++j) {
      float p = ax[j] * (tl * ux[j]) - ax[j];  // adj*(t*u - 1), exact for adj in {0,1}
      rs += p;
      af[j] = f2bf(p);
    }
#pragma unroll
    for (int n = 0; n < 8; ++n)
      acc[n] = __builtin_amdgcn_mfma_f32_16x16x32_bf16(af, bf[n], acc[n], 0, 0, 0);

    a0 = na0; a1 = na1;
#pragma unroll
    for (int n = 0; n < 8; ++n) bf[n] = nbf[n];
  }

  // denominator: reduce A' row-sums across the 4 k-quads (lanes m, m+16, m+32, m+48)
  rs += __shfl_xor(rs, 16);
  rs += __shfl_xor(rs, 32);
  if (chalf == 0 && lane < 16) Lrow[rtile * 16 + lane] = rs;
  __syncthreads();

  float invL[4];
#pragma unroll
  for (int r = 0; r < 4; ++r)
    invL[r] = 1.0f / (Lrow[rtile * 16 + q * 4 + r] + (float)M_);

#pragma unroll
  for (int n = 0; n < 8; ++n) {
    int col = c0 + n * 16 + m;
    float Rc = Rv[col];
#pragma unroll
    for (int r = 0; r < 4; ++r) {
      size_t row = (size_t)blockIdx.x * 32 + rtile * 16 + q * 4 + r;  // C/D: row=(lane>>4)*4+reg
      float v = (acc[n][r] + Rc) * invL[r] + Hf[row * D_ + col];
      attnw[row * D_ + col] = (unsigned short)f2bf(v);
    }
  }
}

// ---------------------------------------------------------------------------
// Final GEMM: out = relu(attn @ Wt^T + bt).  A = attn bf16 [N,D], B[k][n]=Wt[n][k]
// read directly from Wt rows (fp32 -> bf16 in-register). Same 32x256 block shape.
__global__ __launch_bounds__(256, 2) void final_gemm_kernel(
    const unsigned short* __restrict__ attn, const float* __restrict__ Wt,
    const float* __restrict__ bt, float* __restrict__ out) {
  int tid = threadIdx.x;
  int w = tid >> 6, lane = tid & 63;
  int rtile = w & 1, chalf = w >> 1;
  int q = lane >> 4, m = lane & 15;
  int i0 = blockIdx.x * 32 + rtile * 16;
  int c0 = chalf * 128;

  f32x4 acc[8];
#pragma unroll
  for (int n = 0; n < 8; ++n) acc[n] = (f32x4){0.f, 0.f, 0.f, 0.f};

  const unsigned short* arow = attn + (size_t)(i0 + m) * D_;
#pragma unroll
  for (int k0 = 0; k0 < D_; k0 += 32) {
    short8 af = *(const short8*)(arow + k0 + q * 8);
#pragma unroll
    for (int n = 0; n < 8; ++n) {
      const float4* wp = (const float4*)(Wt + (size_t)(c0 + n * 16 + m) * D_ + k0 + q * 8);
      float4 w0 = wp[0], w1 = wp[1];
      short8 bfr;
      bfr[0] = f2bf(w0.x); bfr[1] = f2bf(w0.y); bfr[2] = f2bf(w0.z); bfr[3] = f2bf(w0.w);
      bfr[4] = f2bf(w1.x); bfr[5] = f2bf(w1.y); bfr[6] = f2bf(w1.z); bfr[7] = f2bf(w1.w);
      acc[n] = __builtin_amdgcn_mfma_f32_16x16x32_bf16(af, bfr, acc[n], 0, 0, 0);
    }
  }

#pragma unroll
  for (int n = 0; n < 8; ++n) {
    int col = c0 + n * 16 + m;
    float b = bt[col];
#pragma unroll
    for (int r = 0; r < 4; ++r) {
      size_t row = (size_t)blockIdx.x * 32 + rtile * 16 + q * 4 + r;
      float v = acc[n][r] + b;
      out[row * O_ + col] = fmaxf(v, 0.0f);
    }
  }
}

// ---------------------------------------------------------------------------
extern "C" void kernel_launch(void* const* d_in, const int* in_sizes, int n_in,
                              void* d_out, int out_size, void* d_ws, size_t ws_size,
                              hipStream_t stream) {
  const float* Hf  = (const float*)d_in[0];  // [N,D]
  const float* Hc  = (const float*)d_in[1];  // [M,D]
  const float* adj = (const float*)d_in[2];  // [N,M]
  const float* wa  = (const float*)d_in[3];  // [2D]
  const float* ba  = (const float*)d_in[4];  // [1]
  const float* Wt  = (const float*)d_in[5];  // [O,D]
  const float* bt  = (const float*)d_in[6];  // [O]
  float* out = (float*)d_out;

  char* ws = (char*)d_ws;
  float* tv = (float*)(ws + WS_T);
  float* uv = (float*)(ws + WS_U);
  float* Rv = (float*)(ws + WS_R);
  unsigned short* HcT  = (unsigned short*)(ws + WS_HCT);
  unsigned short* attn = (unsigned short*)(ws + WS_ATTN);

  hipMemsetAsync(Rv, 0, D_ * sizeof(float), stream);  // atomic target

  rowdot_exp_kernel<<<N_ / 4, 256, 0, stream>>>(Hf, wa, ba, tv);          // t = exp(sf+ba)
  rowdot_exp_kernel<<<M_ / 4, 256, 0, stream>>>(Hc, wa + D_, nullptr, uv);// u = exp(sc)
  transpose_hc_kernel<<<256, 256, 0, stream>>>(Hc, HcT, Rv);

  main_gemm_kernel<<<N_ / 32, 256, 0, stream>>>(adj, HcT, tv, uv, Rv, Hf, attn);
  final_gemm_kernel<<<N_ / 32, 256, 0, stream>>>(attn, Wt, bt, out);
}

// Round 2
// 566.612 us; speedup vs baseline: 1.3192x; 1.3192x over previous
//
#include <hip/hip_runtime.h>
#include <hip/hip_bf16.h>
#include <stdint.h>

// Problem constants (fixed by the reference)
#define N_ 16384
#define M_ 4096
#define D_ 256
#define O_ 256

// Workspace layout (bytes)
#define WS_T    0            // float[N]        exp(sf+ba)
#define WS_U    (64*1024)    // float[M]        exp(sc)
#define WS_R    (80*1024)    // float[D]        colsum(Hc)
#define WS_WTP  (96*1024)    // ushort[8*16*64*8]   Wt packed fragments (128 KB)
#define WS_BP   (256*1024)   // ushort[128*16*64*8] Hc packed fragments (2 MB)

typedef float  f32x4  __attribute__((ext_vector_type(4)));
typedef short  short8 __attribute__((ext_vector_type(8)));

// fp32 -> bf16 (RNE). Inputs are finite (random normals) so no NaN handling.
__device__ __forceinline__ short f2bf(float f) {
  uint32_t u = __float_as_uint(f);
  u += 0x7FFFu + ((u >> 16) & 1u);
  return (short)(u >> 16);
}

// ---------------------------------------------------------------------------
// Prep 1: per-row dot with weight vector, then exp(dot + bias).
// One wave per row; lane l handles 4 consecutive elements (D=256 = 64*4).
__global__ __launch_bounds__(256) void rowdot_exp_kernel(
    const float* __restrict__ X, const float* __restrict__ w,
    const float* __restrict__ bias, float* __restrict__ outv) {
  int wv = threadIdx.x >> 6, lane = threadIdx.x & 63;
  int row = blockIdx.x * 4 + wv;
  const float4* x4 = (const float4*)(X + (size_t)row * D_);
  const float4* w4 = (const float4*)w;
  float4 xa = x4[lane], wa4 = w4[lane];
  float s = xa.x * wa4.x + xa.y * wa4.y + xa.z * wa4.z + xa.w * wa4.w;
#pragma unroll
  for (int off = 32; off > 0; off >>= 1) s += __shfl_xor(s, off);
  if (lane == 0) outv[row] = expf(s + (bias ? bias[0] : 0.0f));
}

// ---------------------------------------------------------------------------
// Prep 2: Hc [M,D] fp32 -> BP fragment-major bf16 + R = colsum(Hc).
// BP layout: BP[((k0g*16 + cg)*64 + lane)*8 + j] = bf16(Hc[k0g*32+q*8+j][cg*16+m])
// with lane = q*16+m  (exactly the MFMA B-fragment each lane needs, so the
// main kernel's fragment load is base + lane*16B: fully coalesced 1KB/instr).
__global__ __launch_bounds__(256) void hc_pack_kernel(
    const float* __restrict__ Hc, unsigned short* __restrict__ BP,
    float* __restrict__ R) {
  __shared__ float tile[64][65];
  __shared__ float red[4][64];
  int bk = blockIdx.x >> 2;   // 64 tiles along M (k)
  int bc = blockIdx.x & 3;    // 4 tiles along D (col)
  int k0 = bk * 64, col0 = bc * 64;
  int t = threadIdx.x;
  int lane = t & 63, wv = t >> 6;
  int m = lane & 15, q = lane >> 4;
  float colsum = 0.0f;
#pragma unroll
  for (int i = 0; i < 16; ++i) {
    int e = t + 256 * i;
    int kk = e >> 6, cc = e & 63;            // cc == t&63 (constant per thread)
    float v = Hc[(size_t)(k0 + kk) * D_ + col0 + cc];
    tile[kk][cc] = v;
    colsum += v;
  }
  red[wv][t & 63] = colsum;
  __syncthreads();
  if (t < 64)
    atomicAdd(&R[col0 + t], red[0][t] + red[1][t] + red[2][t] + red[3][t]);
#pragma unroll
  for (int t8 = 0; t8 < 2; ++t8) {
    int tile_id = t8 * 4 + wv;               // 8 (sub,g) fragment tiles
    int sub = tile_id >> 2, g = tile_id & 3;
    int kgg = bk * 2 + sub;                  // global k0g (32-k block)
    int cgg = bc * 4 + g;                    // global colgroup (16 cols)
    short8 v8;
#pragma unroll
    for (int j = 0; j < 8; ++j)
      v8[j] = f2bf(tile[sub * 32 + q * 8 + j][g * 16 + m]);
    *(short8*)(BP + ((size_t)(kgg * 16 + cgg) * 64 + lane) * 8) = v8;
  }
}

// ---------------------------------------------------------------------------
// Prep 3: Wt [O,D] fp32 -> WtP fragment-major bf16 (same layout as BP,
// k0g in 0..7, cg in 0..15). 8192 fragment-lanes total.
__global__ __launch_bounds__(256) void wt_pack_kernel(
    const float* __restrict__ Wt, unsigned short* __restrict__ WtP) {
  int t = blockIdx.x * 256 + threadIdx.x;    // 0..8191
  int lane = t & 63, cg = (t >> 6) & 15, kg = t >> 10;
  int m = lane & 15, q = lane >> 4;
  const float* src = Wt + (size_t)(cg * 16 + m) * D_ + kg * 32 + q * 8;
  float4 w0 = *(const float4*)src, w1 = *(const float4*)(src + 4);
  short8 v8;
  v8[0] = f2bf(w0.x); v8[1] = f2bf(w0.y); v8[2] = f2bf(w0.z); v8[3] = f2bf(w0.w);
  v8[4] = f2bf(w1.x); v8[5] = f2bf(w1.y); v8[6] = f2bf(w1.z); v8[7] = f2bf(w1.w);
  *(short8*)(WtP + (size_t)t * 8) = v8;
}

// ---------------------------------------------------------------------------
// Fused main kernel:
//   C = A' @ Hc  with A'_ij = adj_ij*(t_i*u_j - 1) built in registers
//   attn = (C + R)/(rowsum(A') + M) + Hf        -> staged in LDS (bf16)
//   out  = relu(attn @ Wt^T + bt)               -> fp32 global
// Block: 256 thr = 4 waves; wave = (rtile = 16 rows, chalf = 128 cols).
// Grid = N/32 = 512 blocks (2/CU). K-loop: no barriers, depth-2 register
// prefetch (unroll-2 rotation) to hide adj HBM latency. All fragment loads
// coalesced (BP/WtP prepacked, adj contiguous 32B/lane).
__global__ __launch_bounds__(256, 2) void main_fused_kernel(
    const float* __restrict__ adj, const unsigned short* __restrict__ BP,
    const float* __restrict__ tv, const float* __restrict__ uv,
    const float* __restrict__ Rv, const float* __restrict__ Hf,
    const unsigned short* __restrict__ WtP, const float* __restrict__ bt,
    float* __restrict__ out) {
  __shared__ float u_lds[M_];
  __shared__ float Lrow[32];
  __shared__ alignas(16) unsigned short attn_lds[32][264];  // +8 pad

  int tid = threadIdx.x;
  int w = tid >> 6, lane = tid & 63;
  int rtile = w & 1, chalf = w >> 1;
  int q = lane >> 4, m = lane & 15;
  int koff = q * 8;

  for (int i = tid; i < M_; i += 256) u_lds[i] = uv[i];

  int i0 = blockIdx.x * 32 + rtile * 16;
  float tl = tv[i0 + m];
  const float* adjrow = adj + (size_t)(i0 + m) * M_ + koff;
  const unsigned short* bwave = BP + chalf * 4096 + lane * 8;
  int c0 = chalf * 128;

  f32x4 acc[8];
#pragma unroll
  for (int n = 0; n < 8; ++n) acc[n] = (f32x4){0.f, 0.f, 0.f, 0.f};
  float rs = 0.0f;

  __syncthreads();  // u_lds ready

  // prefetch set0 (k=0) and set1 (k=32)
  float4 a00 = *(const float4*)(adjrow);
  float4 a01 = *(const float4*)(adjrow + 4);
  float4 a10 = *(const float4*)(adjrow + 32);
  float4 a11 = *(const float4*)(adjrow + 36);
  short8 b0[8], b1[8];
#pragma unroll
  for (int n = 0; n < 8; ++n) b0[n] = *(const short8*)(bwave + n * 512);
#pragma unroll
  for (int n = 0; n < 8; ++n) b1[n] = *(const short8*)(bwave + 8192 + n * 512);

  for (int k0 = 0; k0 < M_; k0 += 64) {
    // ---- half A: consume k0, prefetch k0+64 into set0
    {
      float4 u0 = *(const float4*)&u_lds[k0 + koff];
      float4 u1 = *(const float4*)&u_lds[k0 + koff + 4];
      float ax[8] = {a00.x, a00.y, a00.z, a00.w, a01.x, a01.y, a01.z, a01.w};
      float ux[8] = {u0.x, u0.y, u0.z, u0.w, u1.x, u1.y, u1.z, u1.w};
      short8 af;
#pragma unroll
      for (int j = 0; j < 8; ++j) {
        float p = ax[j] * (tl * ux[j]) - ax[j];  // adj*(t*u - 1), exact for adj in {0,1}
        rs += p;
        af[j] = f2bf(p);
      }
#pragma unroll
      for (int n = 0; n < 8; ++n)
        acc[n] = __builtin_amdgcn_mfma_f32_16x16x32_bf16(af, b0[n], acc[n], 0, 0, 0);
      int kp = k0 + 64; if (kp >= M_) kp = 0;  // last iter: harmless reload of k=0
      a00 = *(const float4*)(adjrow + kp);
      a01 = *(const float4*)(adjrow + kp + 4);
      const unsigned short* bp = bwave + (size_t)(kp >> 5) * 8192;
#pragma unroll
      for (int n = 0; n < 8; ++n) b0[n] = *(const short8*)(bp + n * 512);
    }
    // ---- half B: consume k0+32, prefetch k0+96 into set1
    {
      float4 u0 = *(const float4*)&u_lds[k0 + 32 + koff];
      float4 u1 = *(const float4*)&u_lds[k0 + 32 + koff + 4];
      float ax[8] = {a10.x, a10.y, a10.z, a10.w, a11.x, a11.y, a11.z, a11.w};
      float ux[8] = {u0.x, u0.y, u0.z, u0.w, u1.x, u1.y, u1.z, u1.w};
      short8 af;
#pragma unroll
      for (int j = 0; j < 8; ++j) {
        float p = ax[j] * (tl * ux[j]) - ax[j];
        rs += p;
        af[j] = f2bf(p);
      }
#pragma unroll
      for (int n = 0; n < 8; ++n)
        acc[n] = __builtin_amdgcn_mfma_f32_16x16x32_bf16(af, b1[n], acc[n], 0, 0, 0);
      int kp = k0 + 96; if (kp >= M_) kp = 0;
      a10 = *(const float4*)(adjrow + kp);
      a11 = *(const float4*)(adjrow + kp + 4);
      const unsigned short* bp = bwave + (size_t)(kp >> 5) * 8192;
#pragma unroll
      for (int n = 0; n < 8; ++n) b1[n] = *(const short8*)(bp + n * 512);
    }
  }

  // softmax denominator: reduce A' row-sums across the 4 k-quads
  rs += __shfl_xor(rs, 16);
  rs += __shfl_xor(rs, 32);
  if (chalf == 0 && lane < 16) Lrow[rtile * 16 + lane] = rs;
  __syncthreads();

  float invL[4];
#pragma unroll
  for (int r = 0; r < 4; ++r)
    invL[r] = 1.0f / (Lrow[rtile * 16 + q * 4 + r] + (float)M_);

  // epilogue: attn = (C + R)/L + Hf, bf16 -> LDS (A-operand layout for final GEMM)
#pragma unroll
  for (int n = 0; n < 8; ++n) {
    int col = c0 + n * 16 + m;
    float Rc = Rv[col];
#pragma unroll
    for (int r = 0; r < 4; ++r) {
      int rloc = rtile * 16 + q * 4 + r;     // C/D layout: row=(lane>>4)*4+reg
      size_t row = (size_t)blockIdx.x * 32 + rloc;
      float v = (acc[n][r] + Rc) * invL[r] + Hf[row * D_ + col];
      attn_lds[rloc][col] = (unsigned short)f2bf(v);
    }
  }
  __syncthreads();

  // final GEMM: out = relu(attn @ Wt^T + bt); K = 256 = 8 k-steps
  f32x4 facc[8];
#pragma unroll
  for (int n = 0; n < 8; ++n) facc[n] = (f32x4){0.f, 0.f, 0.f, 0.f};
  const unsigned short* wwave = WtP + chalf * 4096 + lane * 8;
#pragma unroll
  for (int kf = 0; kf < 8; ++kf) {
    short8 af = *(const short8*)&attn_lds[rtile * 16 + m][kf * 32 + koff];
#pragma unroll
    for (int n = 0; n < 8; ++n)
      facc[n] = __builtin_amdgcn_mfma_f32_16x16x32_bf16(
          af, *(const short8*)(wwave + kf * 8192 + n * 512), facc[n], 0, 0, 0);
  }
#pragma unroll
  for (int n = 0; n < 8; ++n) {
    int col = c0 + n * 16 + m;
    float b = bt[col];
#pragma unroll
    for (int r = 0; r < 4; ++r) {
      size_t row = (size_t)blockIdx.x * 32 + rtile * 16 + q * 4 + r;
      out[row * O_ + col] = fmaxf(facc[n][r] + b, 0.0f);
    }
  }
}

// ---------------------------------------------------------------------------
extern "C" void kernel_launch(void* const* d_in, const int* in_sizes, int n_in,
                              void* d_out, int out_size, void* d_ws, size_t ws_size,
                              hipStream_t stream) {
  const float* Hf  = (const float*)d_in[0];  // [N,D]
  const float* Hc  = (const float*)d_in[1];  // [M,D]
  const float* adj = (const float*)d_in[2];  // [N,M]
  const float* wa  = (const float*)d_in[3];  // [2D]
  const float* ba  = (const float*)d_in[4];  // [1]
  const float* Wt  = (const float*)d_in[5];  // [O,D]
  const float* bt  = (const float*)d_in[6];  // [O]
  float* out = (float*)d_out;

  char* ws = (char*)d_ws;
  float* tv = (float*)(ws + WS_T);
  float* uv = (float*)(ws + WS_U);
  float* Rv = (float*)(ws + WS_R);
  unsigned short* WtP = (unsigned short*)(ws + WS_WTP);
  unsigned short* BP  = (unsigned short*)(ws + WS_BP);

  hipMemsetAsync(Rv, 0, D_ * sizeof(float), stream);  // atomic target

  rowdot_exp_kernel<<<N_ / 4, 256, 0, stream>>>(Hf, wa, ba, tv);           // t = exp(sf+ba)
  rowdot_exp_kernel<<<M_ / 4, 256, 0, stream>>>(Hc, wa + D_, nullptr, uv); // u = exp(sc)
  hc_pack_kernel<<<256, 256, 0, stream>>>(Hc, BP, Rv);
  wt_pack_kernel<<<32, 256, 0, stream>>>(Wt, WtP);

  main_fused_kernel<<<N_ / 32, 256, 0, stream>>>(adj, BP, tv, uv, Rv, Hf, WtP, bt, out);
}

// Round 3
// 537.250 us; speedup vs baseline: 1.3913x; 1.0547x over previous
//
#include <hip/hip_runtime.h>
#include <hip/hip_bf16.h>
#include <stdint.h>

// Problem constants (fixed by the reference)
#define N_ 16384
#define M_ 4096
#define D_ 256
#define O_ 256

// Workspace layout (bytes)
#define WS_T    0            // float[N]        exp(sf+ba)
#define WS_U    (64*1024)    // float[M]        exp(sc)
#define WS_R    (80*1024)    // float[D]        colsum(Hc)
#define WS_WTP  (96*1024)    // ushort[8*16*64*8]   Wt packed fragments (128 KB)
#define WS_BP   (256*1024)   // ushort[128*16*64*8] Hc packed fragments (2 MB)

typedef float  f32x4  __attribute__((ext_vector_type(4)));
typedef short  short8 __attribute__((ext_vector_type(8)));

// fp32 -> bf16 (RNE). Inputs are finite so no NaN handling.
__device__ __forceinline__ unsigned short f2bf(float f) {
  uint32_t u = __float_as_uint(f);
  u += 0x7FFFu + ((u >> 16) & 1u);
  return (unsigned short)(u >> 16);
}
__device__ __forceinline__ uint32_t pack2bf(float a, float b) {
  return (uint32_t)f2bf(a) | ((uint32_t)f2bf(b) << 16);
}

// async global->LDS, 16 B/lane: LDS dst = wave-uniform base + lane*16
__device__ __forceinline__ void gload_lds16(const void* g, void* l) {
  __builtin_amdgcn_global_load_lds(
      (const __attribute__((address_space(1))) void*)g,
      (__attribute__((address_space(3))) void*)l, 16, 0, 0);
}

// ---------------------------------------------------------------------------
// Prep 1: per-row dot with weight vector, then exp(dot + bias).
__global__ __launch_bounds__(256) void rowdot_exp_kernel(
    const float* __restrict__ X, const float* __restrict__ w,
    const float* __restrict__ bias, float* __restrict__ outv) {
  int wv = threadIdx.x >> 6, lane = threadIdx.x & 63;
  int row = blockIdx.x * 4 + wv;
  const float4* x4 = (const float4*)(X + (size_t)row * D_);
  const float4* w4 = (const float4*)w;
  float4 xa = x4[lane], wa4 = w4[lane];
  float s = xa.x * wa4.x + xa.y * wa4.y + xa.z * wa4.z + xa.w * wa4.w;
#pragma unroll
  for (int off = 32; off > 0; off >>= 1) s += __shfl_xor(s, off);
  if (lane == 0) outv[row] = expf(s + (bias ? bias[0] : 0.0f));
}

// ---------------------------------------------------------------------------
// Prep 2: Hc [M,D] fp32 -> BP fragment-major bf16 + R = colsum(Hc).
// BP[((k0g*16 + cg)*64 + lane)*8 + j] = bf16(Hc[k0g*32+q*8+j][cg*16+m]),
// lane = q*16+m  (the exact MFMA B-fragment; loads become base+lane*16B).
__global__ __launch_bounds__(256) void hc_pack_kernel(
    const float* __restrict__ Hc, unsigned short* __restrict__ BP,
    float* __restrict__ R) {
  __shared__ float tile[64][65];
  __shared__ float red[4][64];
  int bk = blockIdx.x >> 2;   // 64 tiles along M (k)
  int bc = blockIdx.x & 3;    // 4 tiles along D (col)
  int k0 = bk * 64, col0 = bc * 64;
  int t = threadIdx.x;
  int lane = t & 63, wv = t >> 6;
  int m = lane & 15, q = lane >> 4;
  float colsum = 0.0f;
#pragma unroll
  for (int i = 0; i < 16; ++i) {
    int e = t + 256 * i;
    int kk = e >> 6, cc = e & 63;
    float v = Hc[(size_t)(k0 + kk) * D_ + col0 + cc];
    tile[kk][cc] = v;
    colsum += v;
  }
  red[wv][t & 63] = colsum;
  __syncthreads();
  if (t < 64)
    atomicAdd(&R[col0 + t], red[0][t] + red[1][t] + red[2][t] + red[3][t]);
#pragma unroll
  for (int t8 = 0; t8 < 2; ++t8) {
    int tile_id = t8 * 4 + wv;
    int sub = tile_id >> 2, g = tile_id & 3;
    int kgg = bk * 2 + sub;
    int cgg = bc * 4 + g;
    short8 v8;
#pragma unroll
    for (int j = 0; j < 8; ++j)
      v8[j] = (short)f2bf(tile[sub * 32 + q * 8 + j][g * 16 + m]);
    *(short8*)(BP + ((size_t)(kgg * 16 + cgg) * 64 + lane) * 8) = v8;
  }
}

// ---------------------------------------------------------------------------
// Prep 3: Wt [O,D] fp32 -> WtP fragment-major bf16 (k0g 0..7, cg 0..15).
__global__ __launch_bounds__(256) void wt_pack_kernel(
    const float* __restrict__ Wt, unsigned short* __restrict__ WtP) {
  int t = blockIdx.x * 256 + threadIdx.x;    // 0..8191
  int lane = t & 63, cg = (t >> 6) & 15, kg = t >> 10;
  int m = lane & 15, q = lane >> 4;
  const float* src = Wt + (size_t)(cg * 16 + m) * D_ + kg * 32 + q * 8;
  float4 w0 = *(const float4*)src, w1 = *(const float4*)(src + 4);
  short8 v8;
  v8[0] = (short)f2bf(w0.x); v8[1] = (short)f2bf(w0.y);
  v8[2] = (short)f2bf(w0.z); v8[3] = (short)f2bf(w0.w);
  v8[4] = (short)f2bf(w1.x); v8[5] = (short)f2bf(w1.y);
  v8[6] = (short)f2bf(w1.z); v8[7] = (short)f2bf(w1.w);
  *(short8*)(WtP + (size_t)t * 8) = v8;
}

// ---------------------------------------------------------------------------
// Fused main kernel, LDS-staged double-buffered structure:
//   A'_ij = adj_ij*(t_i*u_j - 1) transformed ONCE during coalesced staging,
//   written as bf16 fragments to LDS; B tile async-staged (global_load_lds x16B)
//   from prepacked BP; 8 waves (2 rtiles x 4 col-quarters) consume via MFMA.
//   Then attn=(C+R)/(rowsum+M)+Hf -> LDS -> final GEMM vs WtP -> relu -> out.
// BM=32, 512 thr, grid=512 -> 2 blocks/CU, 16 waves/CU (VGPR capped at 128).
// Depth-2 adj register rotation covers HBM latency across the barrier drain.
__global__ __launch_bounds__(512, 4) void main_fused_kernel(
    const float* __restrict__ adj, const unsigned short* __restrict__ BP,
    const float* __restrict__ tv, const float* __restrict__ uv,
    const float* __restrict__ Rv, const float* __restrict__ Hf,
    const unsigned short* __restrict__ WtP, const float* __restrict__ bt,
    float* __restrict__ out) {
  union SM {
    struct {
      unsigned short B[2][16][512];   // [buf][cg][lane*8]   32 KB
      unsigned int   A[2][2][256];    // [buf][rtile][dword]  4 KB
    } st;
    unsigned short attn[32][264];     // 16.9 KB (aliases st after K loop)
  };
  __shared__ SM sm;
  __shared__ float Lrow[32];

  int tid = threadIdx.x;
  int w = tid >> 6, lane = tid & 63;
  int rtile = w & 1, cq = w >> 1;          // MFMA role: 16 rows x 64 cols
  int q = lane >> 4, m = lane & 15;
  int i0 = blockIdx.x * 32;

  // staging role: element (srow, kin..kin+1) of the 32x32 adj tile
  int srow = tid >> 4;                      // 0..31
  int kin  = (tid & 15) * 2;                // 0..30 even
  int rts  = srow >> 4;
  int sdw  = (((kin >> 3) * 16 + (srow & 15)) << 2) + ((kin & 7) >> 1);
  const float* adjp = adj + (size_t)(i0 + srow) * M_ + kin;
  const float* up   = uv + kin;
  float t_reg = tv[i0 + srow];

  f32x4 acc[4];
#pragma unroll
  for (int n = 0; n < 4; ++n) acc[n] = (f32x4){0.f, 0.f, 0.f, 0.f};
  float rs = 0.0f;

  // ---- prologue: stage kc=0 into buf 0
#pragma unroll
  for (int c = 0; c < 2; ++c) {
    int cg = w * 2 + c;
    gload_lds16(BP + ((size_t)cg * 64 + lane) * 8, &sm.st.B[0][cg][0]);
  }
  {
    float2 a0 = *(const float2*)adjp;
    float2 uu = *(const float2*)up;
    float p0 = fmaf(a0.x, t_reg * uu.x, -a0.x);
    float p1 = fmaf(a0.y, t_reg * uu.y, -a0.y);
    rs += p0 + p1;
    sm.st.A[0][rts][sdw] = pack2bf(p0, p1);
  }
  float2 aA = *(const float2*)(adjp + 32);   // adj data for kc=1
  float2 aB = *(const float2*)(adjp + 64);   // adj data for kc=2
  __syncthreads();

  // ---- main K loop: 128 iters of KC=32
  for (int kc = 0; kc < 128; ++kc) {
    int buf = kc & 1, nbuf = buf ^ 1;
    if (kc < 127) {
#pragma unroll
      for (int c = 0; c < 2; ++c) {
        int cg = w * 2 + c;
        gload_lds16(BP + ((size_t)((kc + 1) * 16 + cg) * 64 + lane) * 8,
                    &sm.st.B[nbuf][cg][0]);
      }
    }
    // prefetch adj for kc+3 (used 2 iters from now -> ~2 iters of latency cover)
    int k3 = (kc + 3 < 128) ? (kc + 3) * 32 : 0;
    float2 aC = *(const float2*)(adjp + k3);

    // consume buf
    short8 af = *(const short8*)((const unsigned short*)&sm.st.A[buf][rtile][0] +
                                 (size_t)lane * 8);
#pragma unroll
    for (int n = 0; n < 4; ++n) {
      short8 bf = *(const short8*)&sm.st.B[buf][cq * 4 + n][lane * 8];
      acc[n] = __builtin_amdgcn_mfma_f32_16x16x32_bf16(af, bf, acc[n], 0, 0, 0);
    }

    // transform adj(kc+1) -> A'[nbuf]  (VALU overlaps MFMA pipe)
    if (kc < 127) {
      float2 uu = *(const float2*)(up + (kc + 1) * 32);
      float p0 = fmaf(aA.x, t_reg * uu.x, -aA.x);
      float p1 = fmaf(aA.y, t_reg * uu.y, -aA.y);
      rs += p0 + p1;
      sm.st.A[nbuf][rts][sdw] = pack2bf(p0, p1);
    }
    aA = aB; aB = aC;
    __syncthreads();
  }

  // ---- softmax denominator: rows live in 16-lane groups of each wave
  rs += __shfl_xor(rs, 1);
  rs += __shfl_xor(rs, 2);
  rs += __shfl_xor(rs, 4);
  rs += __shfl_xor(rs, 8);
  if ((lane & 15) == 0) Lrow[w * 4 + (lane >> 4)] = rs;
  __syncthreads();

  float invL[4];
#pragma unroll
  for (int r = 0; r < 4; ++r)
    invL[r] = 1.0f / (Lrow[rtile * 16 + q * 4 + r] + (float)M_);

  // ---- epilogue 1: attn = (C + R)/L + Hf -> LDS bf16 (A-operand layout)
#pragma unroll
  for (int n = 0; n < 4; ++n) {
    int col = cq * 64 + n * 16 + m;
    float Rc = Rv[col];
#pragma unroll
    for (int r = 0; r < 4; ++r) {
      int rloc = rtile * 16 + q * 4 + r;   // C/D: row=(lane>>4)*4+reg
      size_t row = (size_t)i0 + rloc;
      float v = (acc[n][r] + Rc) * invL[r] + Hf[row * D_ + col];
      sm.attn[rloc][col] = f2bf(v);
    }
  }
  __syncthreads();

  // ---- epilogue 2: out = relu(attn @ Wt^T + bt); K = 256 = 8 k-steps
  f32x4 facc[4];
#pragma unroll
  for (int n = 0; n < 4; ++n) facc[n] = (f32x4){0.f, 0.f, 0.f, 0.f};
  const unsigned short* wwave = WtP + (size_t)(cq * 4) * 512 + (size_t)lane * 8;
#pragma unroll
  for (int kf = 0; kf < 8; ++kf) {
    short8 af = *(const short8*)&sm.attn[rtile * 16 + m][kf * 32 + q * 8];
#pragma unroll
    for (int n = 0; n < 4; ++n) {
      short8 bf = *(const short8*)(wwave + ((size_t)kf * 16 + n) * 512);
      facc[n] = __builtin_amdgcn_mfma_f32_16x16x32_bf16(af, bf, facc[n], 0, 0, 0);
    }
  }
#pragma unroll
  for (int n = 0; n < 4; ++n) {
    int col = cq * 64 + n * 16 + m;
    float b = bt[col];
#pragma unroll
    for (int r = 0; r < 4; ++r) {
      size_t row = (size_t)i0 + rtile * 16 + q * 4 + r;
      out[row * O_ + col] = fmaxf(facc[n][r] + b, 0.0f);
    }
  }
}

// ---------------------------------------------------------------------------
extern "C" void kernel_launch(void* const* d_in, const int* in_sizes, int n_in,
                              void* d_out, int out_size, void* d_ws, size_t ws_size,
                              hipStream_t stream) {
  const float* Hf  = (const float*)d_in[0];  // [N,D]
  const float* Hc  = (const float*)d_in[1];  // [M,D]
  const float* adj = (const float*)d_in[2];  // [N,M]
  const float* wa  = (const float*)d_in[3];  // [2D]
  const float* ba  = (const float*)d_in[4];  // [1]
  const float* Wt  = (const float*)d_in[5];  // [O,D]
  const float* bt  = (const float*)d_in[6];  // [O]
  float* out = (float*)d_out;

  char* ws = (char*)d_ws;
  float* tv = (float*)(ws + WS_T);
  float* uv = (float*)(ws + WS_U);
  float* Rv = (float*)(ws + WS_R);
  unsigned short* WtP = (unsigned short*)(ws + WS_WTP);
  unsigned short* BP  = (unsigned short*)(ws + WS_BP);

  hipMemsetAsync(Rv, 0, D_ * sizeof(float), stream);  // atomic target

  rowdot_exp_kernel<<<N_ / 4, 256, 0, stream>>>(Hf, wa, ba, tv);           // t = exp(sf+ba)
  rowdot_exp_kernel<<<M_ / 4, 256, 0, stream>>>(Hc, wa + D_, nullptr, uv); // u = exp(sc)
  hc_pack_kernel<<<256, 256, 0, stream>>>(Hc, BP, Rv);
  wt_pack_kernel<<<32, 256, 0, stream>>>(Wt, WtP);

  main_fused_kernel<<<N_ / 32, 512, 0, stream>>>(adj, BP, tv, uv, Rv, Hf, WtP, bt, out);
}